// Round 17
// baseline (1171.940 us; speedup 1.0000x reference)
//
#include <hip/hip_runtime.h>

#define B_ 8
#define C_ 64
#define HW_ 65536
#define SLOPE_ 0.01f
#define EPS_ 1e-5f
#define CROP_ 244
#define NPIX_ 59536.0f

typedef unsigned short u16;
typedef __attribute__((ext_vector_type(8))) _Float16 f16x8;
typedef __attribute__((ext_vector_type(2))) _Float16 f16x2;
typedef __attribute__((ext_vector_type(4))) float f32x4;

__device__ __forceinline__ int clampi(int v, int lo, int hi) { return v < lo ? lo : (v > hi ? hi : v); }

__device__ __forceinline__ u16 f2h(float f) {
    union { _Float16 h; u16 u; } v; v.h = (_Float16)f; return v.u;
}
__device__ __forceinline__ float h2f(u16 b) {
    union { u16 u; _Float16 h; } v; v.u = b; return (float)v.h;
}
__device__ __forceinline__ f16x2 lrelu2(f16x2 a) {
    const f16x2 z = {(_Float16)0.f, (_Float16)0.f};
    const f16x2 sl = {(_Float16)SLOPE_, (_Float16)SLOPE_};
    return __builtin_elementwise_max(a, z) + sl * __builtin_elementwise_min(a, z);
}

// ---- weight pack: ws (7,oc64,ic64,3,3) fp32 -> wH f16 frag-major
__global__ void wtrans_kernel(const float* __restrict__ ws, u16* __restrict__ wH) {
    int idx = blockIdx.x * 256 + threadIdx.x;
    if (idx >= 7 * 36864) return;
    int l = idx / 36864;
    int rem = idx - l * 36864;
    int frag = rem >> 9;          // tap*8 + kb*4 + mt
    int lj = rem & 511;
    int lane = lj >> 3, j = lj & 7;
    int tap = frag >> 3, kb = (frag >> 2) & 1, mt = frag & 3;
    int oc = (mt << 4) + (lane & 15);
    int ic = (kb << 5) + ((lane >> 4) << 3) + j;
    wH[idx] = f2h(ws[((l * 64 + oc) * 64 + ic) * 9 + tap]);
}

// ---- conv0 + fused stats: 1->64, NHWC f16; stats -> atomic accumulator slot 0
__global__ __launch_bounds__(256) void conv0_kernel(
    const float* __restrict__ xin, const float* __restrict__ w0,
    const float* __restrict__ b0, u16* __restrict__ yout,
    float* __restrict__ accout) {
    __shared__ float w0s[576];          // [tap][oc]
    __shared__ float b0s[64];
    __shared__ u16 s_y[256 * 64];       // 32 KB, XOR-swizzled by (px&7)
    __shared__ float red[4][64][2];
    int tid = threadIdx.x;
    for (int i = tid; i < 576; i += 256) {
        int t = i >> 6, oc = i & 63;
        w0s[i] = w0[oc * 9 + t];
    }
    if (tid < 64) b0s[tid] = b0[tid];
    __syncthreads();
    int b = blockIdx.x & 7;
    int tile = blockIdx.x >> 3;
    int px = (tile << 8) + tid;
    int pxg = (b << 16) + px;
    int y = px >> 8, x = px & 255;
    float xv[9];
#pragma unroll
    for (int ky = 0; ky < 3; ky++)
#pragma unroll
        for (int kx = 0; kx < 3; kx++)
            xv[ky * 3 + kx] = xin[(b << 16) + (clampi(y + ky - 1, 0, 255) << 8) + clampi(x + kx - 1, 0, 255)];
    float acc[64];
#pragma unroll
    for (int k = 0; k < 64; k++) acc[k] = b0s[k];
#pragma unroll
    for (int t = 0; t < 9; t++) {
        float v = xv[t];
        const float4* wt = (const float4*)&w0s[t << 6];
#pragma unroll
        for (int k4 = 0; k4 < 16; k4++) {
            float4 w4 = wt[k4];
            acc[k4 * 4 + 0] = fmaf(v, w4.x, acc[k4 * 4 + 0]);
            acc[k4 * 4 + 1] = fmaf(v, w4.y, acc[k4 * 4 + 1]);
            acc[k4 * 4 + 2] = fmaf(v, w4.z, acc[k4 * 4 + 2]);
            acc[k4 * 4 + 3] = fmaf(v, w4.w, acc[k4 * 4 + 3]);
        }
    }
    uint4* op = (uint4*)(yout + ((size_t)pxg << 6));
#pragma unroll
    for (int c8 = 0; c8 < 8; c8++) {
        uint4 o;
        o.x = (unsigned)f2h(acc[c8 * 8 + 0]) | ((unsigned)f2h(acc[c8 * 8 + 1]) << 16);
        o.y = (unsigned)f2h(acc[c8 * 8 + 2]) | ((unsigned)f2h(acc[c8 * 8 + 3]) << 16);
        o.z = (unsigned)f2h(acc[c8 * 8 + 4]) | ((unsigned)f2h(acc[c8 * 8 + 5]) << 16);
        o.w = (unsigned)f2h(acc[c8 * 8 + 6]) | ((unsigned)f2h(acc[c8 * 8 + 7]) << 16);
        op[c8] = o;
        *(uint4*)(&s_y[(tid << 6) + ((c8 ^ (tid & 7)) << 3)]) = o;
    }
    __syncthreads();
    int pxl = tid >> 3, c8 = tid & 7;
    float s[8], s2[8];
#pragma unroll
    for (int i = 0; i < 8; i++) { s[i] = 0.f; s2[i] = 0.f; }
    for (int it = 0; it < 8; it++) {
        int p = (it << 5) + pxl;
        f16x8 v = *(const f16x8*)(&s_y[(p << 6) + ((c8 ^ (p & 7)) << 3)]);
#pragma unroll
        for (int i = 0; i < 8; i++) {
            float f = (float)v[i];
            s[i] += f; s2[i] += f * f;
        }
    }
#pragma unroll
    for (int msk = 8; msk <= 32; msk <<= 1)
#pragma unroll
        for (int i = 0; i < 8; i++) {
            s[i] += __shfl_xor(s[i], msk);
            s2[i] += __shfl_xor(s2[i], msk);
        }
    int lane = tid & 63, wv = tid >> 6;
    if (lane < 8) {
#pragma unroll
        for (int i = 0; i < 8; i++) {
            red[wv][lane * 8 + i][0] = s[i];
            red[wv][lane * 8 + i][1] = s2[i];
        }
    }
    __syncthreads();
    if (tid < 128) {
        float v = red[0][tid >> 1][tid & 1] + red[1][tid >> 1][tid & 1]
                + red[2][tid >> 1][tid & 1] + red[3][tid >> 1][tid & 1];
        atomicAdd(accout + (b << 7) + tid, v);
    }
}

// ---- mid conv 64->64: 512-thread blocks, 8 waves, 32x16 tile, half-tile pipeline
__global__ __launch_bounds__(512, 4) void conv_mid_kernel(
    const u16* __restrict__ yin, const float* __restrict__ accin,
    const u16* __restrict__ wH, const float* __restrict__ bias,
    u16* __restrict__ yout, float* __restrict__ accout) {
    __shared__ u16 s_in[612 * 64];      // 78336 B; rows 0..33 x 18 cols, swizzled by (px&7)
    __shared__ float s_v[128];
    __shared__ unsigned s_inv2[32];
    __shared__ unsigned s_beta2[32];
    __shared__ float s_bias[64];
    float* s_red = (float*)s_in;        // aliased after all compute: [8][64][2] = 4 KB

    int tid = threadIdx.x;              // 0..511
    int b = blockIdx.x & 7;
    int tile = blockIdx.x >> 3;         // 0..127
    int ty = tile >> 4, tx = tile & 15;
    int y0 = ty << 5, x0 = tx << 4;

    if (tid < 64) {
        s_bias[tid] = bias[tid];
        float s = accin[(b << 7) + (tid << 1)];
        float s2 = accin[(b << 7) + (tid << 1) + 1];
        float mean = s * (1.0f / HW_);
        float var = s2 * (1.0f / HW_) - mean * mean;
        float inv = rsqrtf(var + EPS_);
        s_v[tid * 2] = inv;
        s_v[tid * 2 + 1] = -mean * inv;
    }
    __syncthreads();
    if (tid < 32) {
        int ch = tid << 1;
        union { unsigned u; f16x2 h2; } a, bb;
        a.h2 = (f16x2){(_Float16)s_v[ch * 2], (_Float16)s_v[ch * 2 + 2]};
        bb.h2 = (f16x2){(_Float16)s_v[ch * 2 + 1], (_Float16)s_v[ch * 2 + 3]};
        s_inv2[tid] = a.u;
        s_beta2[tid] = bb.u;
    }
    __syncthreads();

    // ---- phase A staging: halo rows 0..17 (2592 chunk-units over 512 threads)
    for (int chunk = tid; chunk < 2592; chunk += 512) {
        int px = chunk >> 3, c8 = chunk & 7;
        int row = px / 18;
        int col = px - row * 18;
        int iy = clampi(y0 - 1 + row, 0, 255);
        int ix = clampi(x0 - 1 + col, 0, 255);
        union { uint4 q; f16x2 h2[4]; } ui, uo;
        ui.q = *(const uint4*)(yin + ((((size_t)(b << 16)) + (iy << 8) + ix) << 6) + (c8 << 3));
#pragma unroll
        for (int p = 0; p < 4; p++) {
            union { unsigned u; f16x2 h; } iv, bv;
            iv.u = s_inv2[(c8 << 2) + p];
            bv.u = s_beta2[(c8 << 2) + p];
            uo.h2[p] = lrelu2(ui.h2[p] * iv.h + bv.h);
        }
        *(uint4*)(&s_in[(px << 6) + ((c8 ^ (px & 7)) << 3)]) = uo.q;
    }
    __syncthreads();

    int lane = tid & 63, wv = tid >> 6;  // wv 0..7
    int m = lane & 15, q = lane >> 4;

    // ---- register prefetch for halo rows 18..33 (2304 units = 4.5 x 512)
    uint4 pf[5];
#pragma unroll
    for (int k = 0; k < 5; k++) {
        int chunk = 2592 + tid + (k << 9);
        if (chunk < 4896) {
            int px = chunk >> 3, c8 = chunk & 7;
            int row = px / 18;
            int col = px - row * 18;
            int iy = clampi(y0 - 1 + row, 0, 255);
            int ix = clampi(x0 - 1 + col, 0, 255);
            pf[k] = *(const uint4*)(yin + ((((size_t)(b << 16)) + (iy << 8) + ix) << 6) + (c8 << 3));
        }
    }

    // ---- compute A: output rows 0..15 (wave wv -> rows 2wv..2wv+1)
    f32x4 accA[4][2], accB[4][2];
#pragma unroll
    for (int a = 0; a < 4; a++)
#pragma unroll
        for (int c = 0; c < 2; c++) { accA[a][c] = (f32x4){0.f,0.f,0.f,0.f}; accB[a][c] = (f32x4){0.f,0.f,0.f,0.f}; }

    int r0a = wv << 1;
    const f16x8* wfp = (const f16x8*)wH;
#pragma unroll
    for (int t = 0; t < 9; t++) {
        int ky = t / 3, kx = t - ky * 3;
        const f16x8* wn = wfp + (t << 9);
        f16x8 wf[8];
#pragma unroll
        for (int f = 0; f < 8; f++) wf[f] = wn[(f << 6) + lane];
#pragma unroll
        for (int nt = 0; nt < 2; nt++) {
            int p = (r0a + nt + ky) * 18 + kx + m;
            int key = p & 7;
            const u16* pin = &s_in[p << 6];
            f16x8 bf0 = *(const f16x8*)(pin + ((q ^ key) << 3));
            f16x8 bf1 = *(const f16x8*)(pin + (((4 + q) ^ key) << 3));
#pragma unroll
            for (int mt = 0; mt < 4; mt++)
                accA[mt][nt] = __builtin_amdgcn_mfma_f32_16x16x32_f16(wf[mt], bf0, accA[mt][nt], 0, 0, 0);
#pragma unroll
            for (int mt = 0; mt < 4; mt++)
                accA[mt][nt] = __builtin_amdgcn_mfma_f32_16x16x32_f16(wf[4 + mt], bf1, accA[mt][nt], 0, 0, 0);
        }
    }

    // ---- write prefetched rows 18..33 to LDS (disjoint from A-readers: A reads rows <= 17)
#pragma unroll
    for (int k = 0; k < 5; k++) {
        int chunk = 2592 + tid + (k << 9);
        if (chunk < 4896) {
            int px = chunk >> 3, c8 = chunk & 7;
            union { uint4 q; f16x2 h2[4]; } ui, uo;
            ui.q = pf[k];
#pragma unroll
            for (int p = 0; p < 4; p++) {
                union { unsigned u; f16x2 h; } iv, bv;
                iv.u = s_inv2[(c8 << 2) + p];
                bv.u = s_beta2[(c8 << 2) + p];
                uo.h2[p] = lrelu2(ui.h2[p] * iv.h + bv.h);
            }
            *(uint4*)(&s_in[(px << 6) + ((c8 ^ (px & 7)) << 3)]) = uo.q;
        }
    }
    __syncthreads();

    // ---- compute B: output rows 16..31 (wave wv -> rows 16+2wv..17+2wv); taps reversed
    int r0b = 16 + (wv << 1);
#pragma unroll
    for (int tr = 0; tr < 9; tr++) {
        int t = 8 - tr;
        int ky = t / 3, kx = t - ky * 3;
        const f16x8* wn = wfp + (t << 9);
        f16x8 wf[8];
#pragma unroll
        for (int f = 0; f < 8; f++) wf[f] = wn[(f << 6) + lane];
#pragma unroll
        for (int nt = 0; nt < 2; nt++) {
            int p = (r0b + nt + ky) * 18 + kx + m;
            int key = p & 7;
            const u16* pin = &s_in[p << 6];
            f16x8 bf0 = *(const f16x8*)(pin + ((q ^ key) << 3));
            f16x8 bf1 = *(const f16x8*)(pin + (((4 + q) ^ key) << 3));
#pragma unroll
            for (int mt = 0; mt < 4; mt++)
                accB[mt][nt] = __builtin_amdgcn_mfma_f32_16x16x32_f16(wf[mt], bf0, accB[mt][nt], 0, 0, 0);
#pragma unroll
            for (int mt = 0; mt < 4; mt++)
                accB[mt][nt] = __builtin_amdgcn_mfma_f32_16x16x32_f16(wf[4 + mt], bf1, accB[mt][nt], 0, 0, 0);
        }
    }

    // ---- epilogue: bias, NHWC f16 store, per-oc stats (both halves)
    float ss[4][4], sq[4][4];
#pragma unroll
    for (int mt = 0; mt < 4; mt++)
#pragma unroll
        for (int rr = 0; rr < 4; rr++) { ss[mt][rr] = 0.f; sq[mt][rr] = 0.f; }

#pragma unroll
    for (int mt = 0; mt < 4; mt++) {
        int ocb = (mt << 4) + (q << 2);
        float b0v = s_bias[ocb], b1v = s_bias[ocb + 1], b2v = s_bias[ocb + 2], b3v = s_bias[ocb + 3];
#pragma unroll
        for (int half = 0; half < 2; half++) {
#pragma unroll
            for (int nt = 0; nt < 2; nt++) {
                f32x4 v = half ? accB[mt][nt] : accA[mt][nt];
                float v0 = v.x + b0v, v1 = v.y + b1v, v2 = v.z + b2v, v3 = v.w + b3v;
                uint2 o;
                o.x = (unsigned)f2h(v0) | ((unsigned)f2h(v1) << 16);
                o.y = (unsigned)f2h(v2) | ((unsigned)f2h(v3) << 16);
                int y = y0 + (half ? r0b : r0a) + nt, x = x0 + m;
                *(uint2*)(yout + ((((size_t)(b << 16)) + (y << 8) + x) << 6) + ocb) = o;
                ss[mt][0] += v0; ss[mt][1] += v1; ss[mt][2] += v2; ss[mt][3] += v3;
                sq[mt][0] += v0 * v0; sq[mt][1] += v1 * v1; sq[mt][2] += v2 * v2; sq[mt][3] += v3 * v3;
            }
        }
    }
#pragma unroll
    for (int mt = 0; mt < 4; mt++)
#pragma unroll
        for (int rr = 0; rr < 4; rr++) {
#pragma unroll
            for (int msk = 1; msk <= 8; msk <<= 1) {
                ss[mt][rr] += __shfl_xor(ss[mt][rr], msk);
                sq[mt][rr] += __shfl_xor(sq[mt][rr], msk);
            }
        }
    __syncthreads();   // all s_in reads done before aliased s_red writes
    if (m == 0) {
#pragma unroll
        for (int mt = 0; mt < 4; mt++)
#pragma unroll
            for (int rr = 0; rr < 4; rr++) {
                int oc = (mt << 4) + (q << 2) + rr;
                s_red[(wv * 64 + oc) * 2] = ss[mt][rr];
                s_red[(wv * 64 + oc) * 2 + 1] = sq[mt][rr];
            }
    }
    __syncthreads();
    if (tid < 128) {
        float v = 0.f;
#pragma unroll
        for (int w = 0; w < 8; w++)
            v += s_red[(w * 64 + (tid >> 1)) * 2 + (tid & 1)];
        atomicAdd(accout + (b << 7) + tid, v);
    }
}

// ---- projection 64->1 + residual: single-pass staging; stats from accumulator
__global__ __launch_bounds__(256, 2) void proj_kernel(
    const u16* __restrict__ y7, const float* __restrict__ accin,
    const float* __restrict__ wp, const float* __restrict__ bp,
    const float* __restrict__ xin, float* __restrict__ out) {
    __shared__ u16 s_a[612 * 64];       // 18x34 halo, swizzled
    __shared__ float s_v[128];
    __shared__ unsigned s_inv2[32];
    __shared__ unsigned s_beta2[32];
    __shared__ unsigned s_w2[288];

    int tid = threadIdx.x;
    int b = blockIdx.x & 7, t = blockIdx.x >> 3;
    int ys = t >> 3, xsp = t & 7;
    int y0 = ys << 4, x0 = xsp << 5;

    if (tid < 64) {
        float s = accin[(b << 7) + (tid << 1)];
        float s2 = accin[(b << 7) + (tid << 1) + 1];
        float mean = s * (1.0f / HW_);
        float var = s2 * (1.0f / HW_) - mean * mean;
        float inv = rsqrtf(var + EPS_);
        s_v[tid * 2] = inv;
        s_v[tid * 2 + 1] = -mean * inv;
    }
    __syncthreads();
    if (tid < 32) {
        int ch = tid << 1;
        union { unsigned u; f16x2 h2; } a, bb;
        a.h2 = (f16x2){(_Float16)s_v[ch * 2], (_Float16)s_v[ch * 2 + 2]};
        bb.h2 = (f16x2){(_Float16)s_v[ch * 2 + 1], (_Float16)s_v[ch * 2 + 3]};
        s_inv2[tid] = a.u;
        s_beta2[tid] = bb.u;
    }
    for (int i = tid; i < 288; i += 256) {
        int pr = i / 9, tap = i - pr * 9;
        int ch = pr << 1;
        s_w2[i] = (unsigned)f2h(wp[ch * 9 + tap]) | ((unsigned)f2h(wp[(ch + 1) * 9 + tap]) << 16);
    }
    __syncthreads();

    for (int chunk = tid; chunk < 4896; chunk += 256) {
        int px = chunk >> 3, c8 = chunk & 7;
        int row = px / 34;
        int col = px - row * 34;
        int iy = clampi(y0 - 1 + row, 0, 255);
        int ix = clampi(x0 - 1 + col, 0, 255);
        union { uint4 q; f16x2 h2[4]; } ui, uo;
        ui.q = *(const uint4*)(y7 + ((((size_t)(b << 16)) + (iy << 8) + ix) << 6) + (c8 << 3));
#pragma unroll
        for (int p = 0; p < 4; p++) {
            union { unsigned u; f16x2 h; } iv, bv;
            iv.u = s_inv2[(c8 << 2) + p];
            bv.u = s_beta2[(c8 << 2) + p];
            uo.h2[p] = lrelu2(ui.h2[p] * iv.h + bv.h);
        }
        *(uint4*)(&s_a[(px << 6) + ((c8 ^ (px & 7)) << 3)]) = uo.q;
    }
    __syncthreads();

    float bias0 = bp[0];
#pragma unroll
    for (int half = 0; half < 2; half++) {
        int idx = (half << 8) + tid;
        int py = idx >> 5, pxx = idx & 31;
        float acc = bias0;
#pragma unroll
        for (int ky = 0; ky < 3; ky++)
#pragma unroll
            for (int kx = 0; kx < 3; kx++) {
                int p = (py + ky) * 34 + pxx + kx;
                int key = p & 7;
                const u16* pin = &s_a[p << 6];
                int tap = ky * 3 + kx;
#pragma unroll
                for (int c8 = 0; c8 < 8; c8++) {
                    f16x8 v = *(const f16x8*)(pin + ((c8 ^ key) << 3));
#pragma unroll
                    for (int i2 = 0; i2 < 4; i2++) {
                        unsigned wu = s_w2[((c8 << 2) + i2) * 9 + tap];
                        acc = fmaf((float)v[2 * i2], h2f((u16)(wu & 0xffff)), acc);
                        acc = fmaf((float)v[2 * i2 + 1], h2f((u16)(wu >> 16)), acc);
                    }
                }
            }
        int pxg = (b << 16) + ((y0 + py) << 8) + x0 + pxx;
        out[pxg] = acc + xin[pxg];
    }
}

// ---- loss stage 1: per (b, strip of 4 rows, oy): accumulate 13 ox offsets from LDS
__global__ __launch_bounds__(256) void loss_strip_kernel(
    const float* __restrict__ hr, const float* __restrict__ target,
    float* __restrict__ partial2) {
    __shared__ float s_hr[4][256];
    __shared__ float s_t[4][244];
    __shared__ float s_r2[4][13][2];

    int tid = threadIdx.x;
    int b = blockIdx.x & 7;
    int rest = blockIdx.x >> 3;
    int oy = rest % 13;
    int strip = rest / 13;
    int y0 = strip << 2;

    for (int i = tid; i < 1024; i += 256) {
        int r = i >> 8, x = i & 255;
        s_hr[r][x] = hr[(b << 16) + ((y0 + oy + r) << 8) + x];
    }
    for (int i = tid; i < 976; i += 256) {
        int r = i / 244, x = i - r * 244;
        s_t[r][x] = target[(b << 16) + ((y0 + r + 6) << 8) + 6 + x];
    }
    __syncthreads();

    float s[13], s2[13];
#pragma unroll
    for (int o = 0; o < 13; o++) { s[o] = 0.f; s2[o] = 0.f; }
    if (tid < 244) {
#pragma unroll
        for (int r = 0; r < 4; r++) {
            float tv = s_t[r][tid];
#pragma unroll
            for (int o = 0; o < 13; o++) {
                float d = s_hr[r][tid + o] - tv;
                s[o] += d; s2[o] += d * d;
            }
        }
    }
#pragma unroll
    for (int msk = 1; msk < 64; msk <<= 1)
#pragma unroll
        for (int o = 0; o < 13; o++) {
            s[o] += __shfl_xor(s[o], msk);
            s2[o] += __shfl_xor(s2[o], msk);
        }
    int lane = tid & 63, wv = tid >> 6;
    if (lane == 0) {
#pragma unroll
        for (int o = 0; o < 13; o++) { s_r2[wv][o][0] = s[o]; s_r2[wv][o][1] = s2[o]; }
    }
    __syncthreads();
    if (tid < 26) {
        int o = tid >> 1, k = tid & 1;
        float v = s_r2[0][o][k] + s_r2[1][o][k] + s_r2[2][o][k] + s_r2[3][o][k];
        int off = oy * 13 + o;
        partial2[(((b * 61 + strip) * 169) + off) * 2 + k] = v;
    }
}

// ---- loss stage 2: reduce 61 strips -> per-(off,b) loss
__global__ __launch_bounds__(64) void loss_mid_kernel(
    const float* __restrict__ partial2, float* __restrict__ lossM) {
    int b = blockIdx.x & 7, off = blockIdx.x >> 3;
    int lane = threadIdx.x;
    float s = 0.f, s2 = 0.f;
    if (lane < 61) {
        const float* p = partial2 + (((b * 61 + lane) * 169) + off) * 2;
        s = p[0]; s2 = p[1];
    }
#pragma unroll
    for (int msk = 1; msk < 64; msk <<= 1) { s += __shfl_xor(s, msk); s2 += __shfl_xor(s2, msk); }
    if (lane == 0) {
        float m = s * (1.0f / NPIX_);
        lossM[off * 8 + b] = s2 * (1.0f / NPIX_) - m * m;
    }
}

__global__ void loss_final_kernel(const float* __restrict__ lossM, float* __restrict__ out) {
    int b = threadIdx.x;
    float mn = 0.f;
    if (b < 8) {
        mn = 1e30f;
        for (int off = 0; off < 169; off++) mn = fminf(mn, lossM[off * 8 + b]);
    }
#pragma unroll
    for (int msk = 1; msk < 8; msk <<= 1) mn += __shfl_xor(mn, msk);
    if (b == 0) out[0] = mn * 0.125f;
}

extern "C" void kernel_launch(void* const* d_in, const int* in_sizes, int n_in,
                              void* d_out, int out_size, void* d_ws, size_t ws_size,
                              hipStream_t stream) {
    const float* xIn    = (const float*)d_in[0];
    const float* target = (const float*)d_in[1];
    const float* w0     = (const float*)d_in[2];
    const float* b0     = (const float*)d_in[3];
    const float* wsAll  = (const float*)d_in[4];
    const float* bsAll  = (const float*)d_in[5];
    const float* wp     = (const float*)d_in[6];
    const float* bp     = (const float*)d_in[7];
    float* out = (float*)d_out;

    float* normacc  = (float*)d_ws;                 // 8 slots x 1024 f (32 KB)
    float* partial2 = normacc + 8192;               // 164,944 f
    float* lossM    = partial2 + 164944;            // 1,352 f
    u16*  wH        = (u16*)(lossM + 1352);         // 258,048 u16
    u16*  bufA      = wH + 258048;                  // 64 MiB
    u16*  bufB      = bufA + 33554432;              // 64 MiB

    hipMemsetAsync(normacc, 0, 8192 * sizeof(float), stream);
    wtrans_kernel<<<1008, 256, 0, stream>>>(wsAll, wH);
    conv0_kernel<<<2048, 256, 0, stream>>>(xIn, w0, b0, bufA, normacc);
    for (int l = 0; l < 7; l++) {
        const u16* in = (l & 1) ? bufB : bufA;
        u16* o = (l & 1) ? bufA : bufB;
        conv_mid_kernel<<<1024, 512, 0, stream>>>(
            in, normacc + l * 1024, wH + l * 36864, bsAll + l * 64, o, normacc + (l + 1) * 1024);
    }
    proj_kernel<<<1024, 256, 0, stream>>>(bufB, normacc + 7 * 1024, wp, bp, xIn, out);
    loss_strip_kernel<<<6344, 256, 0, stream>>>(out, target, partial2);
    loss_mid_kernel<<<1352, 64, 0, stream>>>(partial2, lossM);
    loss_final_kernel<<<1, 64, 0, stream>>>(lossM, out + 524288);
}

// Round 18
// 645.366 us; speedup vs baseline: 1.8159x; 1.8159x over previous
//
#include <hip/hip_runtime.h>

#define B_ 8
#define C_ 64
#define HW_ 65536
#define SLOPE_ 0.01f
#define EPS_ 1e-5f
#define CROP_ 244
#define NPIX_ 59536.0f

typedef unsigned short u16;
typedef __attribute__((ext_vector_type(8))) _Float16 f16x8;
typedef __attribute__((ext_vector_type(2))) _Float16 f16x2;
typedef __attribute__((ext_vector_type(4))) float f32x4;

__device__ __forceinline__ int clampi(int v, int lo, int hi) { return v < lo ? lo : (v > hi ? hi : v); }

__device__ __forceinline__ u16 f2h(float f) {
    union { _Float16 h; u16 u; } v; v.h = (_Float16)f; return v.u;
}
__device__ __forceinline__ float h2f(u16 b) {
    union { u16 u; _Float16 h; } v; v.u = b; return (float)v.h;
}
__device__ __forceinline__ f16x2 lrelu2(f16x2 a) {
    const f16x2 z = {(_Float16)0.f, (_Float16)0.f};
    const f16x2 sl = {(_Float16)SLOPE_, (_Float16)SLOPE_};
    return __builtin_elementwise_max(a, z) + sl * __builtin_elementwise_min(a, z);
}

// ---- weight pack: ws (7,oc64,ic64,3,3) fp32 -> wH f16 frag-major
__global__ void wtrans_kernel(const float* __restrict__ ws, u16* __restrict__ wH) {
    int idx = blockIdx.x * 256 + threadIdx.x;
    if (idx >= 7 * 36864) return;
    int l = idx / 36864;
    int rem = idx - l * 36864;
    int frag = rem >> 9;          // tap*8 + kb*4 + mt
    int lj = rem & 511;
    int lane = lj >> 3, j = lj & 7;
    int tap = frag >> 3, kb = (frag >> 2) & 1, mt = frag & 3;
    int oc = (mt << 4) + (lane & 15);
    int ic = (kb << 5) + ((lane >> 4) << 3) + j;
    wH[idx] = f2h(ws[((l * 64 + oc) * 64 + ic) * 9 + tap]);
}

// ---- conv0 + fused stats: 1->64, NHWC f16; stats -> atomic accumulator slot 0
__global__ __launch_bounds__(256) void conv0_kernel(
    const float* __restrict__ xin, const float* __restrict__ w0,
    const float* __restrict__ b0, u16* __restrict__ yout,
    float* __restrict__ accout) {
    __shared__ float w0s[576];          // [tap][oc]
    __shared__ float b0s[64];
    __shared__ u16 s_y[256 * 64];       // 32 KB, XOR-swizzled by (px&7)
    __shared__ float red[4][64][2];
    int tid = threadIdx.x;
    for (int i = tid; i < 576; i += 256) {
        int t = i >> 6, oc = i & 63;
        w0s[i] = w0[oc * 9 + t];
    }
    if (tid < 64) b0s[tid] = b0[tid];
    __syncthreads();
    int b = blockIdx.x & 7;
    int tile = blockIdx.x >> 3;
    int px = (tile << 8) + tid;
    int pxg = (b << 16) + px;
    int y = px >> 8, x = px & 255;
    float xv[9];
#pragma unroll
    for (int ky = 0; ky < 3; ky++)
#pragma unroll
        for (int kx = 0; kx < 3; kx++)
            xv[ky * 3 + kx] = xin[(b << 16) + (clampi(y + ky - 1, 0, 255) << 8) + clampi(x + kx - 1, 0, 255)];
    float acc[64];
#pragma unroll
    for (int k = 0; k < 64; k++) acc[k] = b0s[k];
#pragma unroll
    for (int t = 0; t < 9; t++) {
        float v = xv[t];
        const float4* wt = (const float4*)&w0s[t << 6];
#pragma unroll
        for (int k4 = 0; k4 < 16; k4++) {
            float4 w4 = wt[k4];
            acc[k4 * 4 + 0] = fmaf(v, w4.x, acc[k4 * 4 + 0]);
            acc[k4 * 4 + 1] = fmaf(v, w4.y, acc[k4 * 4 + 1]);
            acc[k4 * 4 + 2] = fmaf(v, w4.z, acc[k4 * 4 + 2]);
            acc[k4 * 4 + 3] = fmaf(v, w4.w, acc[k4 * 4 + 3]);
        }
    }
    uint4* op = (uint4*)(yout + ((size_t)pxg << 6));
#pragma unroll
    for (int c8 = 0; c8 < 8; c8++) {
        uint4 o;
        o.x = (unsigned)f2h(acc[c8 * 8 + 0]) | ((unsigned)f2h(acc[c8 * 8 + 1]) << 16);
        o.y = (unsigned)f2h(acc[c8 * 8 + 2]) | ((unsigned)f2h(acc[c8 * 8 + 3]) << 16);
        o.z = (unsigned)f2h(acc[c8 * 8 + 4]) | ((unsigned)f2h(acc[c8 * 8 + 5]) << 16);
        o.w = (unsigned)f2h(acc[c8 * 8 + 6]) | ((unsigned)f2h(acc[c8 * 8 + 7]) << 16);
        op[c8] = o;
        *(uint4*)(&s_y[(tid << 6) + ((c8 ^ (tid & 7)) << 3)]) = o;
    }
    __syncthreads();
    int pxl = tid >> 3, c8 = tid & 7;
    float s[8], s2[8];
#pragma unroll
    for (int i = 0; i < 8; i++) { s[i] = 0.f; s2[i] = 0.f; }
    for (int it = 0; it < 8; it++) {
        int p = (it << 5) + pxl;
        f16x8 v = *(const f16x8*)(&s_y[(p << 6) + ((c8 ^ (p & 7)) << 3)]);
#pragma unroll
        for (int i = 0; i < 8; i++) {
            float f = (float)v[i];
            s[i] += f; s2[i] += f * f;
        }
    }
#pragma unroll
    for (int msk = 8; msk <= 32; msk <<= 1)
#pragma unroll
        for (int i = 0; i < 8; i++) {
            s[i] += __shfl_xor(s[i], msk);
            s2[i] += __shfl_xor(s2[i], msk);
        }
    int lane = tid & 63, wv = tid >> 6;
    if (lane < 8) {
#pragma unroll
        for (int i = 0; i < 8; i++) {
            red[wv][lane * 8 + i][0] = s[i];
            red[wv][lane * 8 + i][1] = s2[i];
        }
    }
    __syncthreads();
    if (tid < 128) {
        float v = red[0][tid >> 1][tid & 1] + red[1][tid >> 1][tid & 1]
                + red[2][tid >> 1][tid & 1] + red[3][tid >> 1][tid & 1];
        atomicAdd(accout + (b << 7) + tid, v);
    }
}

// ---- mid conv 64->64: LDS-staged 32x16 tile, half-tile pipeline; stats via atomics
__global__ __launch_bounds__(256, 2) void conv_mid_kernel(
    const u16* __restrict__ yin, const float* __restrict__ accin,
    const u16* __restrict__ wH, const float* __restrict__ bias,
    u16* __restrict__ yout, float* __restrict__ accout) {
    __shared__ u16 s_in[612 * 64];      // 78336 B; rows 0..33 x 18 cols, swizzled by (px&7)
    __shared__ float s_v[128];
    __shared__ unsigned s_inv2[32];
    __shared__ unsigned s_beta2[32];
    __shared__ float s_bias[64];
    __shared__ float s_red[512];

    int tid = threadIdx.x;
    int b = blockIdx.x & 7;
    int tile = blockIdx.x >> 3;         // 0..127
    int ty = tile >> 4, tx = tile & 15;
    int y0 = ty << 5, x0 = tx << 4;

    if (tid < 64) {
        s_bias[tid] = bias[tid];
        float s = accin[(b << 7) + (tid << 1)];
        float s2 = accin[(b << 7) + (tid << 1) + 1];
        float mean = s * (1.0f / HW_);
        float var = s2 * (1.0f / HW_) - mean * mean;
        float inv = rsqrtf(var + EPS_);
        s_v[tid * 2] = inv;
        s_v[tid * 2 + 1] = -mean * inv;
    }
    __syncthreads();
    if (tid < 32) {
        int ch = tid << 1;
        union { unsigned u; f16x2 h2; } a, bb;
        a.h2 = (f16x2){(_Float16)s_v[ch * 2], (_Float16)s_v[ch * 2 + 2]};
        bb.h2 = (f16x2){(_Float16)s_v[ch * 2 + 1], (_Float16)s_v[ch * 2 + 3]};
        s_inv2[tid] = a.u;
        s_beta2[tid] = bb.u;
    }
    __syncthreads();

    // ---- phase A staging: halo rows 0..17 (2592 chunk-units)
    for (int chunk = tid; chunk < 2592; chunk += 256) {
        int px = chunk >> 3, c8 = chunk & 7;
        int row = px / 18;
        int col = px - row * 18;
        int iy = clampi(y0 - 1 + row, 0, 255);
        int ix = clampi(x0 - 1 + col, 0, 255);
        union { uint4 q; f16x2 h2[4]; } ui, uo;
        ui.q = *(const uint4*)(yin + ((((size_t)(b << 16)) + (iy << 8) + ix) << 6) + (c8 << 3));
#pragma unroll
        for (int p = 0; p < 4; p++) {
            union { unsigned u; f16x2 h; } iv, bv;
            iv.u = s_inv2[(c8 << 2) + p];
            bv.u = s_beta2[(c8 << 2) + p];
            uo.h2[p] = lrelu2(ui.h2[p] * iv.h + bv.h);
        }
        *(uint4*)(&s_in[(px << 6) + ((c8 ^ (px & 7)) << 3)]) = uo.q;
    }
    __syncthreads();

    int lane = tid & 63, wv = tid >> 6;
    int m = lane & 15, q = lane >> 4;

    // ---- register prefetch for halo rows 18..33 (2304 units = 9 x 256)
    uint4 pf[9];
    int pfc8[9];
    int pfpx[9];
#pragma unroll
    for (int k = 0; k < 9; k++) {
        int chunk = 2592 + tid + (k << 8);
        int px = chunk >> 3, c8 = chunk & 7;
        int row = px / 18;
        int col = px - row * 18;
        int iy = clampi(y0 - 1 + row, 0, 255);
        int ix = clampi(x0 - 1 + col, 0, 255);
        pf[k] = *(const uint4*)(yin + ((((size_t)(b << 16)) + (iy << 8) + ix) << 6) + (c8 << 3));
        pfc8[k] = c8; pfpx[k] = px;
    }

    // ---- compute A: output rows 0..15
    f32x4 accA[4][4], accB[4][4];
#pragma unroll
    for (int a = 0; a < 4; a++)
#pragma unroll
        for (int c = 0; c < 4; c++) { accA[a][c] = (f32x4){0.f,0.f,0.f,0.f}; accB[a][c] = (f32x4){0.f,0.f,0.f,0.f}; }

    int r0a = wv << 2;
    const f16x8* wfp = (const f16x8*)wH;
#pragma unroll
    for (int t = 0; t < 9; t++) {
        int ky = t / 3, kx = t - ky * 3;
        const f16x8* wn = wfp + (t << 9);
        f16x8 wf[8];
#pragma unroll
        for (int f = 0; f < 8; f++) wf[f] = wn[(f << 6) + lane];
#pragma unroll
        for (int nt = 0; nt < 4; nt++) {
            int p = (r0a + nt + ky) * 18 + kx + m;
            int key = p & 7;
            const u16* pin = &s_in[p << 6];
            f16x8 bf0 = *(const f16x8*)(pin + ((q ^ key) << 3));
            f16x8 bf1 = *(const f16x8*)(pin + (((4 + q) ^ key) << 3));
#pragma unroll
            for (int mt = 0; mt < 4; mt++)
                accA[mt][nt] = __builtin_amdgcn_mfma_f32_16x16x32_f16(wf[mt], bf0, accA[mt][nt], 0, 0, 0);
#pragma unroll
            for (int mt = 0; mt < 4; mt++)
                accA[mt][nt] = __builtin_amdgcn_mfma_f32_16x16x32_f16(wf[4 + mt], bf1, accA[mt][nt], 0, 0, 0);
        }
    }

    // ---- write prefetched rows 18..33 to LDS (disjoint from A-readers)
#pragma unroll
    for (int k = 0; k < 9; k++) {
        int c8 = pfc8[k], px = pfpx[k];
        union { uint4 q; f16x2 h2[4]; } ui, uo;
        ui.q = pf[k];
#pragma unroll
        for (int p = 0; p < 4; p++) {
            union { unsigned u; f16x2 h; } iv, bv;
            iv.u = s_inv2[(c8 << 2) + p];
            bv.u = s_beta2[(c8 << 2) + p];
            uo.h2[p] = lrelu2(ui.h2[p] * iv.h + bv.h);
        }
        *(uint4*)(&s_in[(px << 6) + ((c8 ^ (px & 7)) << 3)]) = uo.q;
    }
    __syncthreads();

    // ---- compute B: output rows 16..31; taps reversed (L1-hot weights)
    int r0b = 16 + (wv << 2);
#pragma unroll
    for (int tr = 0; tr < 9; tr++) {
        int t = 8 - tr;
        int ky = t / 3, kx = t - ky * 3;
        const f16x8* wn = wfp + (t << 9);
        f16x8 wf[8];
#pragma unroll
        for (int f = 0; f < 8; f++) wf[f] = wn[(f << 6) + lane];
#pragma unroll
        for (int nt = 0; nt < 4; nt++) {
            int p = (r0b + nt + ky) * 18 + kx + m;
            int key = p & 7;
            const u16* pin = &s_in[p << 6];
            f16x8 bf0 = *(const f16x8*)(pin + ((q ^ key) << 3));
            f16x8 bf1 = *(const f16x8*)(pin + (((4 + q) ^ key) << 3));
#pragma unroll
            for (int mt = 0; mt < 4; mt++)
                accB[mt][nt] = __builtin_amdgcn_mfma_f32_16x16x32_f16(wf[mt], bf0, accB[mt][nt], 0, 0, 0);
#pragma unroll
            for (int mt = 0; mt < 4; mt++)
                accB[mt][nt] = __builtin_amdgcn_mfma_f32_16x16x32_f16(wf[4 + mt], bf1, accB[mt][nt], 0, 0, 0);
        }
    }

    // ---- epilogue: bias, NHWC f16 store, per-oc stats (both halves)
    float ss[4][4], sq[4][4];
#pragma unroll
    for (int mt = 0; mt < 4; mt++)
#pragma unroll
        for (int rr = 0; rr < 4; rr++) { ss[mt][rr] = 0.f; sq[mt][rr] = 0.f; }

#pragma unroll
    for (int mt = 0; mt < 4; mt++) {
        int ocb = (mt << 4) + (q << 2);
        float b0v = s_bias[ocb], b1v = s_bias[ocb + 1], b2v = s_bias[ocb + 2], b3v = s_bias[ocb + 3];
#pragma unroll
        for (int half = 0; half < 2; half++) {
#pragma unroll
            for (int nt = 0; nt < 4; nt++) {
                f32x4 v = half ? accB[mt][nt] : accA[mt][nt];
                float v0 = v.x + b0v, v1 = v.y + b1v, v2 = v.z + b2v, v3 = v.w + b3v;
                uint2 o;
                o.x = (unsigned)f2h(v0) | ((unsigned)f2h(v1) << 16);
                o.y = (unsigned)f2h(v2) | ((unsigned)f2h(v3) << 16);
                int y = y0 + (half ? r0b : r0a) + nt, x = x0 + m;
                *(uint2*)(yout + ((((size_t)(b << 16)) + (y << 8) + x) << 6) + ocb) = o;
                ss[mt][0] += v0; ss[mt][1] += v1; ss[mt][2] += v2; ss[mt][3] += v3;
                sq[mt][0] += v0 * v0; sq[mt][1] += v1 * v1; sq[mt][2] += v2 * v2; sq[mt][3] += v3 * v3;
            }
        }
    }
#pragma unroll
    for (int mt = 0; mt < 4; mt++)
#pragma unroll
        for (int rr = 0; rr < 4; rr++) {
#pragma unroll
            for (int msk = 1; msk <= 8; msk <<= 1) {
                ss[mt][rr] += __shfl_xor(ss[mt][rr], msk);
                sq[mt][rr] += __shfl_xor(sq[mt][rr], msk);
            }
        }
    if (m == 0) {
#pragma unroll
        for (int mt = 0; mt < 4; mt++)
#pragma unroll
            for (int rr = 0; rr < 4; rr++) {
                int oc = (mt << 4) + (q << 2) + rr;
                s_red[(wv * 64 + oc) * 2] = ss[mt][rr];
                s_red[(wv * 64 + oc) * 2 + 1] = sq[mt][rr];
            }
    }
    __syncthreads();
    if (tid < 128) {
        float v = s_red[(0 * 64 + (tid >> 1)) * 2 + (tid & 1)] + s_red[(1 * 64 + (tid >> 1)) * 2 + (tid & 1)]
                + s_red[(2 * 64 + (tid >> 1)) * 2 + (tid & 1)] + s_red[(3 * 64 + (tid >> 1)) * 2 + (tid & 1)];
        atomicAdd(accout + (b << 7) + tid, v);
    }
}

// ---- projection 64->1 + residual: single-pass staging; stats from accumulator
__global__ __launch_bounds__(256, 2) void proj_kernel(
    const u16* __restrict__ y7, const float* __restrict__ accin,
    const float* __restrict__ wp, const float* __restrict__ bp,
    const float* __restrict__ xin, float* __restrict__ out) {
    __shared__ u16 s_a[612 * 64];       // 18x34 halo, swizzled
    __shared__ float s_v[128];
    __shared__ unsigned s_inv2[32];
    __shared__ unsigned s_beta2[32];
    __shared__ unsigned s_w2[288];

    int tid = threadIdx.x;
    int b = blockIdx.x & 7, t = blockIdx.x >> 3;
    int ys = t >> 3, xsp = t & 7;
    int y0 = ys << 4, x0 = xsp << 5;

    if (tid < 64) {
        float s = accin[(b << 7) + (tid << 1)];
        float s2 = accin[(b << 7) + (tid << 1) + 1];
        float mean = s * (1.0f / HW_);
        float var = s2 * (1.0f / HW_) - mean * mean;
        float inv = rsqrtf(var + EPS_);
        s_v[tid * 2] = inv;
        s_v[tid * 2 + 1] = -mean * inv;
    }
    __syncthreads();
    if (tid < 32) {
        int ch = tid << 1;
        union { unsigned u; f16x2 h2; } a, bb;
        a.h2 = (f16x2){(_Float16)s_v[ch * 2], (_Float16)s_v[ch * 2 + 2]};
        bb.h2 = (f16x2){(_Float16)s_v[ch * 2 + 1], (_Float16)s_v[ch * 2 + 3]};
        s_inv2[tid] = a.u;
        s_beta2[tid] = bb.u;
    }
    for (int i = tid; i < 288; i += 256) {
        int pr = i / 9, tap = i - pr * 9;
        int ch = pr << 1;
        s_w2[i] = (unsigned)f2h(wp[ch * 9 + tap]) | ((unsigned)f2h(wp[(ch + 1) * 9 + tap]) << 16);
    }
    __syncthreads();

    for (int chunk = tid; chunk < 4896; chunk += 256) {
        int px = chunk >> 3, c8 = chunk & 7;
        int row = px / 34;
        int col = px - row * 34;
        int iy = clampi(y0 - 1 + row, 0, 255);
        int ix = clampi(x0 - 1 + col, 0, 255);
        union { uint4 q; f16x2 h2[4]; } ui, uo;
        ui.q = *(const uint4*)(y7 + ((((size_t)(b << 16)) + (iy << 8) + ix) << 6) + (c8 << 3));
#pragma unroll
        for (int p = 0; p < 4; p++) {
            union { unsigned u; f16x2 h; } iv, bv;
            iv.u = s_inv2[(c8 << 2) + p];
            bv.u = s_beta2[(c8 << 2) + p];
            uo.h2[p] = lrelu2(ui.h2[p] * iv.h + bv.h);
        }
        *(uint4*)(&s_a[(px << 6) + ((c8 ^ (px & 7)) << 3)]) = uo.q;
    }
    __syncthreads();

    float bias0 = bp[0];
#pragma unroll
    for (int half = 0; half < 2; half++) {
        int idx = (half << 8) + tid;
        int py = idx >> 5, pxx = idx & 31;
        float acc = bias0;
#pragma unroll
        for (int ky = 0; ky < 3; ky++)
#pragma unroll
            for (int kx = 0; kx < 3; kx++) {
                int p = (py + ky) * 34 + pxx + kx;
                int key = p & 7;
                const u16* pin = &s_a[p << 6];
                int tap = ky * 3 + kx;
#pragma unroll
                for (int c8 = 0; c8 < 8; c8++) {
                    f16x8 v = *(const f16x8*)(pin + ((c8 ^ key) << 3));
#pragma unroll
                    for (int i2 = 0; i2 < 4; i2++) {
                        unsigned wu = s_w2[((c8 << 2) + i2) * 9 + tap];
                        acc = fmaf((float)v[2 * i2], h2f((u16)(wu & 0xffff)), acc);
                        acc = fmaf((float)v[2 * i2 + 1], h2f((u16)(wu >> 16)), acc);
                    }
                }
            }
        int pxg = (b << 16) + ((y0 + py) << 8) + x0 + pxx;
        out[pxg] = acc + xin[pxg];
    }
}

// ---- loss stage 1: per (b, strip of 4 rows, oy): accumulate 13 ox offsets from LDS
__global__ __launch_bounds__(256) void loss_strip_kernel(
    const float* __restrict__ hr, const float* __restrict__ target,
    float* __restrict__ partial2) {
    __shared__ float s_hr[4][256];
    __shared__ float s_t[4][244];
    __shared__ float s_r2[4][13][2];

    int tid = threadIdx.x;
    int b = blockIdx.x & 7;
    int rest = blockIdx.x >> 3;
    int oy = rest % 13;
    int strip = rest / 13;
    int y0 = strip << 2;

    for (int i = tid; i < 1024; i += 256) {
        int r = i >> 8, x = i & 255;
        s_hr[r][x] = hr[(b << 16) + ((y0 + oy + r) << 8) + x];
    }
    for (int i = tid; i < 976; i += 256) {
        int r = i / 244, x = i - r * 244;
        s_t[r][x] = target[(b << 16) + ((y0 + r + 6) << 8) + 6 + x];
    }
    __syncthreads();

    float s[13], s2[13];
#pragma unroll
    for (int o = 0; o < 13; o++) { s[o] = 0.f; s2[o] = 0.f; }
    if (tid < 244) {
#pragma unroll
        for (int r = 0; r < 4; r++) {
            float tv = s_t[r][tid];
#pragma unroll
            for (int o = 0; o < 13; o++) {
                float d = s_hr[r][tid + o] - tv;
                s[o] += d; s2[o] += d * d;
            }
        }
    }
#pragma unroll
    for (int msk = 1; msk < 64; msk <<= 1)
#pragma unroll
        for (int o = 0; o < 13; o++) {
            s[o] += __shfl_xor(s[o], msk);
            s2[o] += __shfl_xor(s2[o], msk);
        }
    int lane = tid & 63, wv = tid >> 6;
    if (lane == 0) {
#pragma unroll
        for (int o = 0; o < 13; o++) { s_r2[wv][o][0] = s[o]; s_r2[wv][o][1] = s2[o]; }
    }
    __syncthreads();
    if (tid < 26) {
        int o = tid >> 1, k = tid & 1;
        float v = s_r2[0][o][k] + s_r2[1][o][k] + s_r2[2][o][k] + s_r2[3][o][k];
        int off = oy * 13 + o;
        partial2[(((b * 61 + strip) * 169) + off) * 2 + k] = v;
    }
}

// ---- loss stage 2: reduce 61 strips -> per-(off,b) loss
__global__ __launch_bounds__(64) void loss_mid_kernel(
    const float* __restrict__ partial2, float* __restrict__ lossM) {
    int b = blockIdx.x & 7, off = blockIdx.x >> 3;
    int lane = threadIdx.x;
    float s = 0.f, s2 = 0.f;
    if (lane < 61) {
        const float* p = partial2 + (((b * 61 + lane) * 169) + off) * 2;
        s = p[0]; s2 = p[1];
    }
#pragma unroll
    for (int msk = 1; msk < 64; msk <<= 1) { s += __shfl_xor(s, msk); s2 += __shfl_xor(s2, msk); }
    if (lane == 0) {
        float m = s * (1.0f / NPIX_);
        lossM[off * 8 + b] = s2 * (1.0f / NPIX_) - m * m;
    }
}

__global__ void loss_final_kernel(const float* __restrict__ lossM, float* __restrict__ out) {
    int b = threadIdx.x;
    float mn = 0.f;
    if (b < 8) {
        mn = 1e30f;
        for (int off = 0; off < 169; off++) mn = fminf(mn, lossM[off * 8 + b]);
    }
#pragma unroll
    for (int msk = 1; msk < 8; msk <<= 1) mn += __shfl_xor(mn, msk);
    if (b == 0) out[0] = mn * 0.125f;
}

extern "C" void kernel_launch(void* const* d_in, const int* in_sizes, int n_in,
                              void* d_out, int out_size, void* d_ws, size_t ws_size,
                              hipStream_t stream) {
    const float* xIn    = (const float*)d_in[0];
    const float* target = (const float*)d_in[1];
    const float* w0     = (const float*)d_in[2];
    const float* b0     = (const float*)d_in[3];
    const float* wsAll  = (const float*)d_in[4];
    const float* bsAll  = (const float*)d_in[5];
    const float* wp     = (const float*)d_in[6];
    const float* bp     = (const float*)d_in[7];
    float* out = (float*)d_out;

    float* normacc  = (float*)d_ws;                 // 8 slots x 1024 f (32 KB)
    float* partial2 = normacc + 8192;               // 164,944 f
    float* lossM    = partial2 + 164944;            // 1,352 f
    u16*  wH        = (u16*)(lossM + 1352);         // 258,048 u16
    u16*  bufA      = wH + 258048;                  // 64 MiB
    u16*  bufB      = bufA + 33554432;              // 64 MiB

    hipMemsetAsync(normacc, 0, 8192 * sizeof(float), stream);
    wtrans_kernel<<<1008, 256, 0, stream>>>(wsAll, wH);
    conv0_kernel<<<2048, 256, 0, stream>>>(xIn, w0, b0, bufA, normacc);
    for (int l = 0; l < 7; l++) {
        const u16* in = (l & 1) ? bufB : bufA;
        u16* o = (l & 1) ? bufA : bufB;
        conv_mid_kernel<<<1024, 256, 0, stream>>>(
            in, normacc + l * 1024, wH + l * 36864, bsAll + l * 64, o, normacc + (l + 1) * 1024);
    }
    proj_kernel<<<1024, 256, 0, stream>>>(bufB, normacc + 7 * 1024, wp, bp, xIn, out);
    loss_strip_kernel<<<6344, 256, 0, stream>>>(out, target, partial2);
    loss_mid_kernel<<<1352, 64, 0, stream>>>(partial2, lossM);
    loss_final_kernel<<<1, 64, 0, stream>>>(lossM, out + 524288);
}